// Round 14
// baseline (176.126 us; speedup 1.0000x reference)
//
#include <hip/hip_runtime.h>

typedef __attribute__((ext_vector_type(4))) int i32x4;
typedef unsigned short u16;
typedef unsigned char u8;
typedef unsigned int u32;
typedef unsigned long long u64;

static constexpr int NROW = 16384;   // b*h*w
static constexpr int NCODE = 8192;
static constexpr int ZN = 4194304;   // b*c*h*w
static constexpr int MARGIN_I = 4200;   // 2.5e-4 * 2^24

// Per-row candidate slots in LDS: 16 groups x GCAP + OCAP overflow = 120 u16.
static constexpr int GCAP = 6;
static constexpr int OCAP = 24;

// workspace layout (bytes)
static constexpr size_t OFF_EB8  = 0;          // i8 granules e  2 MB
static constexpr size_t OFF_LOSS = 2097152;    // float
static constexpr size_t OFF_CTR  = 2097156;    // int

__device__ __forceinline__ char q8(float v, float s) {
  int x = __float2int_rn(v * s);
  x = x < -128 ? -128 : (x > 127 ? 127 : x);
  return (char)x;
}

// max over each 16-lane row via DPP row_ror (VALU pipe, no LDS traffic)
__device__ __forceinline__ int rowmax16(int m) {
  m = max(m, __builtin_amdgcn_update_dpp(m, m, 0x121, 0xf, 0xf, false)); // ror:1
  m = max(m, __builtin_amdgcn_update_dpp(m, m, 0x122, 0xf, 0xf, false)); // ror:2
  m = max(m, __builtin_amdgcn_update_dpp(m, m, 0x124, 0xf, 0xf, false)); // ror:4
  m = max(m, __builtin_amdgcn_update_dpp(m, m, 0x128, 0xf, 0xf, false)); // ror:8
  return m;
}

// ---- numpy fp32 replica (verified rounds 4-9; no FMA contraction) ----
// zr must be 16B-aligned; scalars re-sourced from float4 components in the
// EXACT same operation order as the scalar version (bit-identical).
#pragma clang fp contract(off)
__device__ float np_dist(const float* zr, const float* __restrict__ er, float A) {
  const float4* e4 = (const float4*)er;
  const float4* z4 = (const float4*)zr;
  float s0 = 0.f, s1 = 0.f, s2 = 0.f, s3 = 0.f;
#pragma unroll 4
  for (int i16 = 0; i16 < 16; ++i16) {
    float4 ea = e4[i16 * 4 + 0], eb = e4[i16 * 4 + 1];
    float4 ec = e4[i16 * 4 + 2], ed = e4[i16 * 4 + 3];
    float4 za = z4[i16 * 4 + 0], zb = z4[i16 * 4 + 1];
    float4 zc = z4[i16 * 4 + 2], zd = z4[i16 * 4 + 3];
    s0 = __fadd_rn(__fmul_rn(za.x, ea.x),
         __fadd_rn(__fmul_rn(zb.x, eb.x),
         __fadd_rn(__fmul_rn(zc.x, ec.x),
         __fadd_rn(__fmul_rn(zd.x, ed.x), s0))));
    s1 = __fadd_rn(__fmul_rn(za.y, ea.y),
         __fadd_rn(__fmul_rn(zb.y, eb.y),
         __fadd_rn(__fmul_rn(zc.y, ec.y),
         __fadd_rn(__fmul_rn(zd.y, ed.y), s1))));
    s2 = __fadd_rn(__fmul_rn(za.z, ea.z),
         __fadd_rn(__fmul_rn(zb.z, eb.z),
         __fadd_rn(__fmul_rn(zc.z, ec.z),
         __fadd_rn(__fmul_rn(zd.z, ed.z), s2))));
    s3 = __fadd_rn(__fmul_rn(za.w, ea.w),
         __fadd_rn(__fmul_rn(zb.w, eb.w),
         __fadd_rn(__fmul_rn(zc.w, ec.w),
         __fadd_rn(__fmul_rn(zd.w, ed.w), s3))));
  }
  float C = __fadd_rn(__fadd_rn(s0, s1), __fadd_rn(s2, s3));
  return __fadd_rn(A, -(2.0f * C));
}

// A = np pairwise-sum replica of ||z||^2 (verified rounds 4-9).
__device__ float np_rowA(const float* zrow, int lane, volatile float* red) {
  if (lane < 16) {
    const int half = lane >> 3, jj = lane & 7;
    const float* p = zrow + half * 128 + jj;
    float acc = __fmul_rn(p[0], p[0]);
    for (int i = 8; i < 128; i += 8) acc = __fadd_rn(acc, __fmul_rn(p[i], p[i]));
    red[lane] = acc;
  }
  float h0 = __fadd_rn(__fadd_rn(__fadd_rn(red[0], red[1]), __fadd_rn(red[2], red[3])),
                       __fadd_rn(__fadd_rn(red[4], red[5]), __fadd_rn(red[6], red[7])));
  float h1 = __fadd_rn(__fadd_rn(__fadd_rn(red[8], red[9]), __fadd_rn(red[10], red[11])),
                       __fadd_rn(__fadd_rn(red[12], red[13]), __fadd_rn(red[14], red[15])));
  return __fadd_rn(h0, h1);
}
#pragma clang fp contract(fast)

// ---- kernel 1: e-prep — LDS-transpose requant (round-13 eprep burned ~40us
// on fully uncoalesced 1KB-stride scalar reads; this version reads each code
// row wave-coalesced as float4, quantizes to LDS, then assembles granules and
// writes them coalesced). Output bytes identical to the old mapping:
// granule G = tile*256 + kb*64 + lane holds e[tile*16+l15][kb*64+l4*16+j].
__global__ __launch_bounds__(256) void eprep_kernel(const float* __restrict__ e,
                                                    char* __restrict__ eb8,
                                                    float* __restrict__ loss_ws,
                                                    int* __restrict__ ctr) {
  __shared__ u8 ebuf[64][272];   // 64 code rows x 256 bytes, +16 pad
  const int tid = threadIdx.x;
  const int blk = blockIdx.x;    // 128 blocks x 64 codes (4 tiles)
  if (blk == 0 && tid == 0) { *loss_ws = 0.f; *ctr = 0; }
  const int code0 = blk * 64;
  // phase 1: coalesced float4 reads (64 lanes x 16B = one contiguous 1KB row),
  // quantize (bit-identical q8), store to LDS (2 lanes/bank -> free)
  {
    const int l = tid & 63, rw = tid >> 6;
#pragma unroll 4
    for (int it = 0; it < 16; ++it) {
      const int row = it * 4 + rw;
      const float4 f = *(const float4*)(e + (size_t)(code0 + row) * 256 + l * 4);
      u8* d = &ebuf[row][l * 4];
      d[0] = (u8)q8(f.x, 1048576.0f);
      d[1] = (u8)q8(f.y, 1048576.0f);
      d[2] = (u8)q8(f.z, 1048576.0f);
      d[3] = (u8)q8(f.w, 1048576.0f);
    }
  }
  __syncthreads();
  // phase 2: assemble granules (aligned i32x4 LDS reads), coalesced stores
  i32x4* dst = (i32x4*)(eb8 + (size_t)blk * 16384);
#pragma unroll
  for (int k = 0; k < 4; ++k) {
    const int g = k * 256 + tid;
    const int tt = g >> 8, r = g & 255;
    const int kb = r >> 6, lane = r & 63;
    const int l4 = lane >> 4, l15 = lane & 15;
    dst[g] = *(const i32x4*)&ebuf[tt * 16 + l15][kb * 64 + l4 * 16];
  }
}

// ---- kernel 2: fused scores + rescore (byte-identical to round 13) ----
__global__ __launch_bounds__(512, 2) void fused_kernel(const float* __restrict__ z,
                                                       const char* __restrict__ eb8,
                                                       const float* __restrict__ emb,
                                                       float* __restrict__ loss_ws,
                                                       int* __restrict__ ctr,
                                                       float* __restrict__ z_st,
                                                       float* __restrict__ out_loss,
                                                       float* __restrict__ out_idx) {
  __shared__ float zrows[32][260];
  __shared__ int s_rm[32];
  __shared__ u32 s_cnt[32][16];
  __shared__ u32 s_ovf[32];
  __shared__ u16 s_slots[32][120];   // 16*GCAP=96 group slots + OCAP overflow
  __shared__ float red_s[8][16];
  __shared__ float A_s[32], D_s[32];
  __shared__ u64 best_s[32];
  __shared__ int widx_s[32], starts[33], ovf_list[32], rowtot[32];
  __shared__ int nP, nOvf;
  __shared__ u8 cnts8[32][17];
  __shared__ u16 grpoff[32][17];
  __shared__ u16 pidx[32 * 120];

  const int bh = blockIdx.x;
  const int b = bh >> 5, h = bh & 31;
  const int n0 = bh * 32;
  const int tid = threadIdx.x;
  const int wave = tid >> 6, lane = tid & 63;
  const int l15 = lane & 15, l4 = lane >> 4;

  // ---- prologue: z rows fp32 -> LDS (transposed), init LDS state ----
  {
    const float* src = z + (size_t)b * 262144 + h * 32;
    const int w = tid & 31, c16 = tid >> 5;   // c16: 0..15
#pragma unroll
    for (int c0 = 0; c0 < 256; c0 += 16) {
      int c = c0 + c16;
      zrows[w][c] = src[(size_t)c * 1024 + w];
    }
  }
  if (tid < 32) { s_rm[tid] = INT_MIN; s_ovf[tid] = 0; best_s[tid] = ~0ull; }
  s_cnt[tid >> 4][tid & 15] = 0;   // 512 threads cover [32][16]
  __syncthreads();

  // ---- A fragments: quantize from zrows (float4 reads; bit-identical q8) ----
  i32x4 a[2][4];
#pragma unroll
  for (int rt = 0; rt < 2; ++rt) {
    const float* zr = zrows[rt * 16 + l15];
#pragma unroll
    for (int kb = 0; kb < 4; ++kb) {
      const float4* z4 = (const float4*)(zr + kb * 64 + l4 * 16);
      float4 f0 = z4[0], f1 = z4[1], f2 = z4[2], f3 = z4[3];
      union { char c[16]; i32x4 v; } u;
      u.c[0]  = q8(f0.x, 16.0f); u.c[1]  = q8(f0.y, 16.0f);
      u.c[2]  = q8(f0.z, 16.0f); u.c[3]  = q8(f0.w, 16.0f);
      u.c[4]  = q8(f1.x, 16.0f); u.c[5]  = q8(f1.y, 16.0f);
      u.c[6]  = q8(f1.z, 16.0f); u.c[7]  = q8(f1.w, 16.0f);
      u.c[8]  = q8(f2.x, 16.0f); u.c[9]  = q8(f2.y, 16.0f);
      u.c[10] = q8(f2.z, 16.0f); u.c[11] = q8(f2.w, 16.0f);
      u.c[12] = q8(f3.x, 16.0f); u.c[13] = q8(f3.y, 16.0f);
      u.c[14] = q8(f3.z, 16.0f); u.c[15] = q8(f3.w, 16.0f);
      a[rt][kb] = u.v;
    }
  }

  const i32x4* ebase = (const i32x4*)eb8;
  int lmax[2][4], thr[2][4];

// C-level load (seed only; compiler-managed waits)
#define LOADB_C(CH, B0, B1, B2, B3)                                              \
  {                                                                              \
    const i32x4* bt = ebase + (size_t)((CH) * 8 + wave) * 256;                   \
    B0 = bt[lane]; B1 = bt[64 + lane]; B2 = bt[128 + lane]; B3 = bt[192 + lane]; \
  }

// asm load: one VGPR address + imm offsets; volatile -> not elided/reordered.
#define LOADB_ASM(CH, B0, B1, B2, B3)                                            \
  {                                                                              \
    const char* bt_ = (const char*)(ebase + (size_t)((CH) * 8 + wave) * 256)     \
                      + (size_t)lane * 16;                                       \
    asm volatile("global_load_dwordx4 %0, %1, off"             : "=v"(B0) : "v"(bt_)); \
    asm volatile("global_load_dwordx4 %0, %1, off offset:1024" : "=v"(B1) : "v"(bt_)); \
    asm volatile("global_load_dwordx4 %0, %1, off offset:2048" : "=v"(B2) : "v"(bt_)); \
    asm volatile("global_load_dwordx4 %0, %1, off offset:3072" : "=v"(B3) : "v"(bt_)); \
  }

#define MFMA8(B0, B1, B2, B3, ACC)                                               \
  _Pragma("unroll")                                                              \
  for (int rt = 0; rt < 2; ++rt) {                                               \
    ACC[rt] = __builtin_amdgcn_mfma_i32_16x16x64_i8(a[rt][0], B0, ACC[rt], 0, 0, 0); \
    ACC[rt] = __builtin_amdgcn_mfma_i32_16x16x64_i8(a[rt][1], B1, ACC[rt], 0, 0, 0); \
    ACC[rt] = __builtin_amdgcn_mfma_i32_16x16x64_i8(a[rt][2], B2, ACC[rt], 0, 0, 0); \
    ACC[rt] = __builtin_amdgcn_mfma_i32_16x16x64_i8(a[rt][3], B3, ACC[rt], 0, 0, 0); \
  }

// frozen-threshold check (r6/r7-verified): push iff v > thr; thr only
// refreshed at syncs. Stale thr <= final_max - MARGIN -> superset. lmax is
// local-only (feeds the next sync's atomicMax; monotone union).
#define CHECK8(CH, ACC)                                                          \
  _Pragma("unroll")                                                              \
  for (int rt = 0; rt < 2; ++rt)                                                 \
    _Pragma("unroll")                                                            \
    for (int r = 0; r < 4; ++r) {                                                \
      const int v = ACC[rt][r];                                                  \
      const bool p = v > thr[rt][r];                                             \
      if (__any(p)) {                                                            \
        if (p) {                                                                 \
          const int rl = rt * 16 + l4 * 4 + r;                                   \
          u32 q = atomicAdd(&s_cnt[rl][grp_], 1u);                               \
          if (q < GCAP) {                                                        \
            s_slots[rl][grp_ * GCAP + q] = (u16)((CH) * 128 + wave * 16 + l15);  \
          } else {                                                               \
            u32 o = atomicAdd(&s_ovf[rl], 1u);                                   \
            if (o < OCAP)                                                        \
              s_slots[rl][96 + o] = (u16)((CH) * 128 + wave * 16 + l15);         \
          }                                                                      \
        }                                                                        \
      }                                                                          \
      lmax[rt][r] = max(lmax[rt][r], v);                                         \
    }

// s_rm is monotone (atomicMax only) -> relaxed barrier; LDS-only drain so
// in-flight asm B loads survive the barrier.
#define SYNC_THR()                                                               \
  {                                                                              \
    _Pragma("unroll")                                                            \
    for (int rt = 0; rt < 2; ++rt)                                               \
      _Pragma("unroll")                                                          \
      for (int r = 0; r < 4; ++r) {                                              \
        int m = rowmax16(lmax[rt][r]);                                           \
        if (l15 == 0) atomicMax(&s_rm[rt * 16 + l4 * 4 + r], m);                 \
      }                                                                          \
    asm volatile("s_waitcnt lgkmcnt(0)\n\ts_barrier" ::: "memory");              \
    _Pragma("unroll")                                                            \
    for (int rt = 0; rt < 2; ++rt)                                               \
      _Pragma("unroll")                                                          \
      for (int r = 0; r < 4; ++r)                                                \
        thr[rt][r] = s_rm[rt * 16 + l4 * 4 + r] - MARGIN_I;                      \
  }

  // seed: chunks 0..1, maxes only — warms the threshold
  {
    i32x4 b0, b1, b2, b3;
#pragma unroll 1
    for (int ch = 0; ch < 2; ++ch) {
      LOADB_C(ch, b0, b1, b2, b3);
      i32x4 acc[2] = {{0,0,0,0},{0,0,0,0}};
      MFMA8(b0, b1, b2, b3, acc);
      if (ch == 0) {
#pragma unroll
        for (int rt = 0; rt < 2; ++rt)
#pragma unroll
          for (int r = 0; r < 4; ++r) lmax[rt][r] = acc[rt][r];
      } else {
#pragma unroll
        for (int rt = 0; rt < 2; ++rt)
#pragma unroll
          for (int r = 0; r < 4; ++r) lmax[rt][r] = max(lmax[rt][r], acc[rt][r]);
      }
    }
  }
  SYNC_THR();

  // main: 64 chunks; asm-forced depth-1 pipeline, ping-pong c/n (no ring movs)
  {
    i32x4 c0_, c1_, c2_, c3_, n0_, n1_, n2_, n3_;
    LOADB_ASM(0, c0_, c1_, c2_, c3_);
#pragma unroll 1
    for (int ch = 0; ch < 64; ch += 2) {
      LOADB_ASM(ch + 1, n0_, n1_, n2_, n3_);
      asm volatile("s_waitcnt vmcnt(4)" ::: "memory");   // ch's loads complete
      __builtin_amdgcn_sched_barrier(0);
      {
        i32x4 acc[2] = {{0,0,0,0},{0,0,0,0}};
        MFMA8(c0_, c1_, c2_, c3_, acc);
        const int grp_ = (ch >> 5) * 8 + wave;
        CHECK8(ch, acc);
      }
      if (ch + 2 < 64) {
        LOADB_ASM(ch + 2, c0_, c1_, c2_, c3_);
        asm volatile("s_waitcnt vmcnt(4)" ::: "memory"); // ch+1's loads complete
      } else {
        asm volatile("s_waitcnt vmcnt(0)" ::: "memory");
      }
      __builtin_amdgcn_sched_barrier(0);
      {
        i32x4 acc[2] = {{0,0,0,0},{0,0,0,0}};
        MFMA8(n0_, n1_, n2_, n3_, acc);
        const int grp_ = ((ch + 1) >> 5) * 8 + wave;
        CHECK8(ch + 1, acc);
      }
      if (((ch + 1) & 3) == 3 && (ch + 1) != 63) SYNC_THR();
    }
    asm volatile("s_waitcnt vmcnt(0)" ::: "memory");     // drain before reuse
  }
#undef LOADB_C
#undef LOADB_ASM
#undef MFMA8
#undef CHECK8
#undef SYNC_THR
  __syncthreads();   // all pushes visible

  // ---- rescore phase (verified structure, sourced from LDS) ----
  for (int j = 0; j < 4; ++j) {
    const int r = wave * 4 + j;
    float A = np_rowA(zrows[r], lane, red_s[wave]);
    if (lane == 0) A_s[r] = A;
  }
  if (tid < 32) {
    const int r = tid;
    int tot = 0;
#pragma unroll
    for (int k = 0; k < 16; ++k) {
      int c = (int)s_cnt[r][k];
      int cc = c > GCAP ? GCAP : c;
      cnts8[r][k] = (u8)cc;
      grpoff[r][k] = (u16)tot;
      tot += cc;
    }
    const int ov = (int)s_ovf[r];
    const int oc = ov > OCAP ? OCAP : ov;
    cnts8[r][16] = (u8)oc;
    grpoff[r][16] = (u16)tot;
    tot += oc;
    rowtot[r] = (ov > OCAP) ? 0 : tot;   // 0 -> block-wide full-scan fallback
  }
  __syncthreads();
  if (tid == 0) {
    int acc = 0, no = 0;
    for (int r = 0; r < 32; ++r) {
      starts[r] = acc;
      acc += rowtot[r];
      if (rowtot[r] == 0) ovf_list[no++] = r;
    }
    starts[32] = acc; nP = acc; nOvf = no;
  }
  __syncthreads();
  {
    const int r = tid >> 4, g = tid & 15;   // 512 threads cover [32][16]
    if (rowtot[r]) {
      const int c = cnts8[r][g];
      const int base = starts[r] + grpoff[r][g];
      const int sb = g * GCAP;
      for (int j = 0; j < c; ++j) pidx[base + j] = s_slots[r][sb + j];
    }
  }
  if (tid < 32) {
    const int r = tid;
    if (rowtot[r]) {
      const int c = cnts8[r][16];
      const int base = starts[r] + grpoff[r][16];
      for (int j = 0; j < c; ++j) pidx[base + j] = s_slots[r][96 + j];
    }
  }
  __syncthreads();

  const int P = nP;
  for (int p = tid; p < P; p += 512) {
    // row lookup: largest r with starts[r] <= p (5-step binary search)
    int lo = 0, hi = 32;
#pragma unroll
    for (int s = 0; s < 5; ++s) {
      int mid = (lo + hi) >> 1;
      if (starts[mid] <= p) lo = mid; else hi = mid;
    }
    const int r = lo, idx = (int)pidx[p];
    float D = np_dist(zrows[r], emb + (size_t)idx * 256, A_s[r]);
    u64 key = ((u64)__float_as_uint(D) << 16) | (u32)idx;
    atomicMin(&best_s[r], key);
  }
  __syncthreads();

  // overflow fallback (spill>OCAP, ~never): block-wide scan
  for (int i = 0; i < nOvf; ++i) {
    const int r = ovf_list[i];
    for (int idx = tid; idx < NCODE; idx += 512) {
      float D = np_dist(zrows[r], emb + (size_t)idx * 256, A_s[r]);
      u64 k = ((u64)__float_as_uint(D) << 16) | (u32)idx;
      atomicMin(&best_s[r], k);
    }
  }
  if (nOvf) __syncthreads();

  if (tid < 32) {
    const int r = tid;
    const u64 k = best_s[r];
    const int bidx = (int)(k & 0xFFFF);
    widx_s[r] = bidx;
    out_idx[n0 + r] = (float)bidx;
    D_s[r] = __uint_as_float((u32)(k >> 16));
  }
  __syncthreads();
  if (tid == 0) {
    float s = 0.f;
    for (int r = 0; r < 32; ++r) s += D_s[r];
    atomicAdd(loss_ws, s);
    __threadfence();
    int t = atomicAdd(ctr, 1);
    if (t == 511)
      *out_loss = atomicAdd(loss_ws, 0.0f) * (1.25f / 4194304.0f);
  }

  {
    const int col = tid & 255, hi = tid >> 8;
#pragma unroll
    for (int wi0 = 0; wi0 < 16; ++wi0) {
      const int wi = wi0 * 2 + hi;
      zrows[wi][col] = emb[(size_t)widx_s[wi] * 256 + col];
    }
  }
  __syncthreads();
  {
    const int w = tid & 31, c0 = (tid >> 5) & 7, hi = tid >> 8;
    float* dst = z_st + (size_t)b * 262144 + h * 32 + w;
#pragma unroll
    for (int cj = 0; cj < 16; ++cj) {
      int c = c0 + (cj * 2 + hi) * 8;
      dst[(size_t)c * 1024] = zrows[w][c];
    }
  }
}

extern "C" void kernel_launch(void* const* d_in, const int* in_sizes, int n_in,
                              void* d_out, int out_size, void* d_ws, size_t ws_size,
                              hipStream_t stream) {
  const float* z = (const float*)d_in[0];     // fp32 [16,256,32,32]
  const float* emb = (const float*)d_in[1];   // fp32 [8192,256]
  char* ws = (char*)d_ws;
  char* eb8 = ws + OFF_EB8;
  float* loss_ws = (float*)(ws + OFF_LOSS);
  int* ctr = (int*)(ws + OFF_CTR);
  float* out = (float*)d_out;
  float* out_loss = out + ZN;       // output 1
  float* out_idx = out + ZN + 1;    // output 2

  eprep_kernel<<<128, 256, 0, stream>>>(emb, eb8, loss_ws, ctr);
  fused_kernel<<<512, 512, 0, stream>>>(z, eb8, emb, loss_ws, ctr,
                                        out, out_loss, out_idx);
}

// Round 15
// 171.746 us; speedup vs baseline: 1.0255x; 1.0255x over previous
//
#include <hip/hip_runtime.h>

typedef __attribute__((ext_vector_type(4))) int i32x4;
typedef unsigned short u16;
typedef unsigned char u8;
typedef unsigned int u32;
typedef unsigned long long u64;

static constexpr int NROW = 16384;   // b*h*w
static constexpr int NCODE = 8192;
static constexpr int ZN = 4194304;   // b*c*h*w
static constexpr int MARGIN_I = 4200;   // 2.5e-4 * 2^24

// Per-row candidate slots in LDS: 16 groups x GCAP + OCAP overflow = 160 u16.
// (Enlarged from 6/24 to absorb the extra pushes from 8-chunk threshold
// staleness in the tail; full-scan fallback remains the correctness net.)
static constexpr int GCAP = 8;
static constexpr int OCAP = 32;
static constexpr int GSLOTS = 16 * GCAP;        // 128
static constexpr int SLOTS = GSLOTS + OCAP;     // 160

// workspace layout (bytes)
static constexpr size_t OFF_EB8  = 0;          // i8 granules e  2 MB
static constexpr size_t OFF_LOSS = 2097152;    // float
static constexpr size_t OFF_CTR  = 2097156;    // int

__device__ __forceinline__ char q8(float v, float s) {
  int x = __float2int_rn(v * s);
  x = x < -128 ? -128 : (x > 127 ? 127 : x);
  return (char)x;
}

// max over each 16-lane row via DPP row_ror (VALU pipe, no LDS traffic)
__device__ __forceinline__ int rowmax16(int m) {
  m = max(m, __builtin_amdgcn_update_dpp(m, m, 0x121, 0xf, 0xf, false)); // ror:1
  m = max(m, __builtin_amdgcn_update_dpp(m, m, 0x122, 0xf, 0xf, false)); // ror:2
  m = max(m, __builtin_amdgcn_update_dpp(m, m, 0x124, 0xf, 0xf, false)); // ror:4
  m = max(m, __builtin_amdgcn_update_dpp(m, m, 0x128, 0xf, 0xf, false)); // ror:8
  return m;
}

// ---- numpy fp32 replica (verified rounds 4-9; no FMA contraction) ----
// zr must be 16B-aligned; scalars re-sourced from float4 components in the
// EXACT same operation order as the scalar version (bit-identical).
#pragma clang fp contract(off)
__device__ float np_dist(const float* zr, const float* __restrict__ er, float A) {
  const float4* e4 = (const float4*)er;
  const float4* z4 = (const float4*)zr;
  float s0 = 0.f, s1 = 0.f, s2 = 0.f, s3 = 0.f;
#pragma unroll 4
  for (int i16 = 0; i16 < 16; ++i16) {
    float4 ea = e4[i16 * 4 + 0], eb = e4[i16 * 4 + 1];
    float4 ec = e4[i16 * 4 + 2], ed = e4[i16 * 4 + 3];
    float4 za = z4[i16 * 4 + 0], zb = z4[i16 * 4 + 1];
    float4 zc = z4[i16 * 4 + 2], zd = z4[i16 * 4 + 3];
    s0 = __fadd_rn(__fmul_rn(za.x, ea.x),
         __fadd_rn(__fmul_rn(zb.x, eb.x),
         __fadd_rn(__fmul_rn(zc.x, ec.x),
         __fadd_rn(__fmul_rn(zd.x, ed.x), s0))));
    s1 = __fadd_rn(__fmul_rn(za.y, ea.y),
         __fadd_rn(__fmul_rn(zb.y, eb.y),
         __fadd_rn(__fmul_rn(zc.y, ec.y),
         __fadd_rn(__fmul_rn(zd.y, ed.y), s1))));
    s2 = __fadd_rn(__fmul_rn(za.z, ea.z),
         __fadd_rn(__fmul_rn(zb.z, eb.z),
         __fadd_rn(__fmul_rn(zc.z, ec.z),
         __fadd_rn(__fmul_rn(zd.z, ed.z), s2))));
    s3 = __fadd_rn(__fmul_rn(za.w, ea.w),
         __fadd_rn(__fmul_rn(zb.w, eb.w),
         __fadd_rn(__fmul_rn(zc.w, ec.w),
         __fadd_rn(__fmul_rn(zd.w, ed.w), s3))));
  }
  float C = __fadd_rn(__fadd_rn(s0, s1), __fadd_rn(s2, s3));
  return __fadd_rn(A, -(2.0f * C));
}

// A = np pairwise-sum replica of ||z||^2 (verified rounds 4-9).
__device__ float np_rowA(const float* zrow, int lane, volatile float* red) {
  if (lane < 16) {
    const int half = lane >> 3, jj = lane & 7;
    const float* p = zrow + half * 128 + jj;
    float acc = __fmul_rn(p[0], p[0]);
    for (int i = 8; i < 128; i += 8) acc = __fadd_rn(acc, __fmul_rn(p[i], p[i]));
    red[lane] = acc;
  }
  float h0 = __fadd_rn(__fadd_rn(__fadd_rn(red[0], red[1]), __fadd_rn(red[2], red[3])),
                       __fadd_rn(__fadd_rn(red[4], red[5]), __fadd_rn(red[6], red[7])));
  float h1 = __fadd_rn(__fadd_rn(__fadd_rn(red[8], red[9]), __fadd_rn(red[10], red[11])),
                       __fadd_rn(__fadd_rn(red[12], red[13]), __fadd_rn(red[14], red[15])));
  return __fadd_rn(h0, h1);
}
#pragma clang fp contract(fast)

// ---- kernel 1: e-prep — LDS-transpose requant (coalesced; round 14) ----
__global__ __launch_bounds__(256) void eprep_kernel(const float* __restrict__ e,
                                                    char* __restrict__ eb8,
                                                    float* __restrict__ loss_ws,
                                                    int* __restrict__ ctr) {
  __shared__ u8 ebuf[64][272];   // 64 code rows x 256 bytes, +16 pad
  const int tid = threadIdx.x;
  const int blk = blockIdx.x;    // 128 blocks x 64 codes (4 tiles)
  if (blk == 0 && tid == 0) { *loss_ws = 0.f; *ctr = 0; }
  const int code0 = blk * 64;
  {
    const int l = tid & 63, rw = tid >> 6;
#pragma unroll 4
    for (int it = 0; it < 16; ++it) {
      const int row = it * 4 + rw;
      const float4 f = *(const float4*)(e + (size_t)(code0 + row) * 256 + l * 4);
      u8* d = &ebuf[row][l * 4];
      d[0] = (u8)q8(f.x, 1048576.0f);
      d[1] = (u8)q8(f.y, 1048576.0f);
      d[2] = (u8)q8(f.z, 1048576.0f);
      d[3] = (u8)q8(f.w, 1048576.0f);
    }
  }
  __syncthreads();
  i32x4* dst = (i32x4*)(eb8 + (size_t)blk * 16384);
#pragma unroll
  for (int k = 0; k < 4; ++k) {
    const int g = k * 256 + tid;
    const int tt = g >> 8, r = g & 255;
    const int kb = r >> 6, lane = r & 63;
    const int l4 = lane >> 4, l15 = lane & 15;
    dst[g] = *(const i32x4*)&ebuf[tt * 16 + l15][kb * 64 + l4 * 16];
  }
}

// ---- kernel 2: fused scores + rescore ----
// vs round 14: (a) ONE ballot per chunk (8 cmps OR'd, single wave-uniform
// branch; per-value re-test inside the rare path -> identical push set);
// (b) sync cadence 4 in chunks 0-15, 8 afterwards (9 syncs vs 15) with
// GCAP/OCAP enlarged to 8/32 to absorb the staleness superset.
__global__ __launch_bounds__(512, 2) void fused_kernel(const float* __restrict__ z,
                                                       const char* __restrict__ eb8,
                                                       const float* __restrict__ emb,
                                                       float* __restrict__ loss_ws,
                                                       int* __restrict__ ctr,
                                                       float* __restrict__ z_st,
                                                       float* __restrict__ out_loss,
                                                       float* __restrict__ out_idx) {
  __shared__ float zrows[32][260];
  __shared__ int s_rm[32];
  __shared__ u32 s_cnt[32][16];
  __shared__ u32 s_ovf[32];
  __shared__ u16 s_slots[32][SLOTS];   // 16*GCAP group slots + OCAP overflow
  __shared__ float red_s[8][16];
  __shared__ float A_s[32], D_s[32];
  __shared__ u64 best_s[32];
  __shared__ int widx_s[32], starts[33], ovf_list[32], rowtot[32];
  __shared__ int nP, nOvf;
  __shared__ u8 cnts8[32][17];
  __shared__ u16 grpoff[32][17];
  __shared__ u16 pidx[32 * SLOTS];

  const int bh = blockIdx.x;
  const int b = bh >> 5, h = bh & 31;
  const int n0 = bh * 32;
  const int tid = threadIdx.x;
  const int wave = tid >> 6, lane = tid & 63;
  const int l15 = lane & 15, l4 = lane >> 4;

  // ---- prologue: z rows fp32 -> LDS (transposed), init LDS state ----
  {
    const float* src = z + (size_t)b * 262144 + h * 32;
    const int w = tid & 31, c16 = tid >> 5;   // c16: 0..15
#pragma unroll
    for (int c0 = 0; c0 < 256; c0 += 16) {
      int c = c0 + c16;
      zrows[w][c] = src[(size_t)c * 1024 + w];
    }
  }
  if (tid < 32) { s_rm[tid] = INT_MIN; s_ovf[tid] = 0; best_s[tid] = ~0ull; }
  s_cnt[tid >> 4][tid & 15] = 0;   // 512 threads cover [32][16]
  __syncthreads();

  // ---- A fragments: quantize from zrows (float4 reads; bit-identical q8) ----
  i32x4 a[2][4];
#pragma unroll
  for (int rt = 0; rt < 2; ++rt) {
    const float* zr = zrows[rt * 16 + l15];
#pragma unroll
    for (int kb = 0; kb < 4; ++kb) {
      const float4* z4 = (const float4*)(zr + kb * 64 + l4 * 16);
      float4 f0 = z4[0], f1 = z4[1], f2 = z4[2], f3 = z4[3];
      union { char c[16]; i32x4 v; } u;
      u.c[0]  = q8(f0.x, 16.0f); u.c[1]  = q8(f0.y, 16.0f);
      u.c[2]  = q8(f0.z, 16.0f); u.c[3]  = q8(f0.w, 16.0f);
      u.c[4]  = q8(f1.x, 16.0f); u.c[5]  = q8(f1.y, 16.0f);
      u.c[6]  = q8(f1.z, 16.0f); u.c[7]  = q8(f1.w, 16.0f);
      u.c[8]  = q8(f2.x, 16.0f); u.c[9]  = q8(f2.y, 16.0f);
      u.c[10] = q8(f2.z, 16.0f); u.c[11] = q8(f2.w, 16.0f);
      u.c[12] = q8(f3.x, 16.0f); u.c[13] = q8(f3.y, 16.0f);
      u.c[14] = q8(f3.z, 16.0f); u.c[15] = q8(f3.w, 16.0f);
      a[rt][kb] = u.v;
    }
  }

  const i32x4* ebase = (const i32x4*)eb8;
  int lmax[2][4], thr[2][4];

// C-level load (seed only; compiler-managed waits)
#define LOADB_C(CH, B0, B1, B2, B3)                                              \
  {                                                                              \
    const i32x4* bt = ebase + (size_t)((CH) * 8 + wave) * 256;                   \
    B0 = bt[lane]; B1 = bt[64 + lane]; B2 = bt[128 + lane]; B3 = bt[192 + lane]; \
  }

// asm load: one VGPR address + imm offsets; volatile -> not elided/reordered.
#define LOADB_ASM(CH, B0, B1, B2, B3)                                            \
  {                                                                              \
    const char* bt_ = (const char*)(ebase + (size_t)((CH) * 8 + wave) * 256)     \
                      + (size_t)lane * 16;                                       \
    asm volatile("global_load_dwordx4 %0, %1, off"             : "=v"(B0) : "v"(bt_)); \
    asm volatile("global_load_dwordx4 %0, %1, off offset:1024" : "=v"(B1) : "v"(bt_)); \
    asm volatile("global_load_dwordx4 %0, %1, off offset:2048" : "=v"(B2) : "v"(bt_)); \
    asm volatile("global_load_dwordx4 %0, %1, off offset:3072" : "=v"(B3) : "v"(bt_)); \
  }

#define MFMA8(B0, B1, B2, B3, ACC)                                               \
  _Pragma("unroll")                                                              \
  for (int rt = 0; rt < 2; ++rt) {                                               \
    ACC[rt] = __builtin_amdgcn_mfma_i32_16x16x64_i8(a[rt][0], B0, ACC[rt], 0, 0, 0); \
    ACC[rt] = __builtin_amdgcn_mfma_i32_16x16x64_i8(a[rt][1], B1, ACC[rt], 0, 0, 0); \
    ACC[rt] = __builtin_amdgcn_mfma_i32_16x16x64_i8(a[rt][2], B2, ACC[rt], 0, 0, 0); \
    ACC[rt] = __builtin_amdgcn_mfma_i32_16x16x64_i8(a[rt][3], B3, ACC[rt], 0, 0, 0); \
  }

// frozen-threshold check; ONE wave-uniform ballot gates the whole chunk's push
// path (pushes are rare); per-value re-test inside -> identical push set.
#define CHECK8(CH, ACC)                                                          \
  {                                                                              \
    const bool pa = (ACC[0][0] > thr[0][0]) | (ACC[0][1] > thr[0][1]) |          \
                    (ACC[0][2] > thr[0][2]) | (ACC[0][3] > thr[0][3]) |          \
                    (ACC[1][0] > thr[1][0]) | (ACC[1][1] > thr[1][1]) |          \
                    (ACC[1][2] > thr[1][2]) | (ACC[1][3] > thr[1][3]);           \
    if (__ballot(pa)) {                                                          \
      _Pragma("unroll")                                                          \
      for (int rt = 0; rt < 2; ++rt)                                             \
        _Pragma("unroll")                                                        \
        for (int r = 0; r < 4; ++r) {                                            \
          if (ACC[rt][r] > thr[rt][r]) {                                         \
            const int rl = rt * 16 + l4 * 4 + r;                                 \
            u32 q = atomicAdd(&s_cnt[rl][grp_], 1u);                             \
            if (q < GCAP) {                                                      \
              s_slots[rl][grp_ * GCAP + q] = (u16)((CH) * 128 + wave * 16 + l15);\
            } else {                                                             \
              u32 o = atomicAdd(&s_ovf[rl], 1u);                                 \
              if (o < OCAP)                                                      \
                s_slots[rl][GSLOTS + o] = (u16)((CH) * 128 + wave * 16 + l15);   \
            }                                                                    \
          }                                                                      \
        }                                                                        \
    }                                                                            \
    _Pragma("unroll")                                                            \
    for (int rt = 0; rt < 2; ++rt)                                               \
      _Pragma("unroll")                                                          \
      for (int r = 0; r < 4; ++r)                                                \
        lmax[rt][r] = max(lmax[rt][r], ACC[rt][r]);                              \
  }

// s_rm is monotone (atomicMax only) -> relaxed barrier; LDS-only drain so
// in-flight asm B loads survive the barrier.
#define SYNC_THR()                                                               \
  {                                                                              \
    _Pragma("unroll")                                                            \
    for (int rt = 0; rt < 2; ++rt)                                               \
      _Pragma("unroll")                                                          \
      for (int r = 0; r < 4; ++r) {                                              \
        int m = rowmax16(lmax[rt][r]);                                           \
        if (l15 == 0) atomicMax(&s_rm[rt * 16 + l4 * 4 + r], m);                 \
      }                                                                          \
    asm volatile("s_waitcnt lgkmcnt(0)\n\ts_barrier" ::: "memory");              \
    _Pragma("unroll")                                                            \
    for (int rt = 0; rt < 2; ++rt)                                               \
      _Pragma("unroll")                                                          \
      for (int r = 0; r < 4; ++r)                                                \
        thr[rt][r] = s_rm[rt * 16 + l4 * 4 + r] - MARGIN_I;                      \
  }

  // seed: chunks 0..1, maxes only — warms the threshold
  {
    i32x4 b0, b1, b2, b3;
#pragma unroll 1
    for (int ch = 0; ch < 2; ++ch) {
      LOADB_C(ch, b0, b1, b2, b3);
      i32x4 acc[2] = {{0,0,0,0},{0,0,0,0}};
      MFMA8(b0, b1, b2, b3, acc);
      if (ch == 0) {
#pragma unroll
        for (int rt = 0; rt < 2; ++rt)
#pragma unroll
          for (int r = 0; r < 4; ++r) lmax[rt][r] = acc[rt][r];
      } else {
#pragma unroll
        for (int rt = 0; rt < 2; ++rt)
#pragma unroll
          for (int r = 0; r < 4; ++r) lmax[rt][r] = max(lmax[rt][r], acc[rt][r]);
      }
    }
  }
  SYNC_THR();

  // main: 64 chunks; asm-forced depth-1 pipeline, ping-pong c/n.
  // Syncs after ch in {3,7,11,15,23,31,39,47,55} — dense early (threshold
  // rising fast), sparse late (threshold nearly final).
  {
    i32x4 c0_, c1_, c2_, c3_, n0_, n1_, n2_, n3_;
    LOADB_ASM(0, c0_, c1_, c2_, c3_);
#pragma unroll 1
    for (int ch = 0; ch < 64; ch += 2) {
      LOADB_ASM(ch + 1, n0_, n1_, n2_, n3_);
      asm volatile("s_waitcnt vmcnt(4)" ::: "memory");   // ch's loads complete
      __builtin_amdgcn_sched_barrier(0);
      {
        i32x4 acc[2] = {{0,0,0,0},{0,0,0,0}};
        MFMA8(c0_, c1_, c2_, c3_, acc);
        const int grp_ = (ch >> 5) * 8 + wave;
        CHECK8(ch, acc);
      }
      if (ch + 2 < 64) {
        LOADB_ASM(ch + 2, c0_, c1_, c2_, c3_);
        asm volatile("s_waitcnt vmcnt(4)" ::: "memory"); // ch+1's loads complete
      } else {
        asm volatile("s_waitcnt vmcnt(0)" ::: "memory");
      }
      __builtin_amdgcn_sched_barrier(0);
      {
        i32x4 acc[2] = {{0,0,0,0},{0,0,0,0}};
        MFMA8(n0_, n1_, n2_, n3_, acc);
        const int grp_ = ((ch + 1) >> 5) * 8 + wave;
        CHECK8(ch + 1, acc);
      }
      {
        const int chh = ch + 1;
        if ((((chh & 3) == 3) && chh <= 15) ||
            (((chh & 7) == 7) && chh > 15 && chh != 63)) SYNC_THR();
      }
    }
    asm volatile("s_waitcnt vmcnt(0)" ::: "memory");     // drain before reuse
  }
#undef LOADB_C
#undef LOADB_ASM
#undef MFMA8
#undef CHECK8
#undef SYNC_THR
  __syncthreads();   // all pushes visible

  // ---- rescore phase (verified structure, sourced from LDS) ----
  for (int j = 0; j < 4; ++j) {
    const int r = wave * 4 + j;
    float A = np_rowA(zrows[r], lane, red_s[wave]);
    if (lane == 0) A_s[r] = A;
  }
  if (tid < 32) {
    const int r = tid;
    int tot = 0;
#pragma unroll
    for (int k = 0; k < 16; ++k) {
      int c = (int)s_cnt[r][k];
      int cc = c > GCAP ? GCAP : c;
      cnts8[r][k] = (u8)cc;
      grpoff[r][k] = (u16)tot;
      tot += cc;
    }
    const int ov = (int)s_ovf[r];
    const int oc = ov > OCAP ? OCAP : ov;
    cnts8[r][16] = (u8)oc;
    grpoff[r][16] = (u16)tot;
    tot += oc;
    rowtot[r] = (ov > OCAP) ? 0 : tot;   // 0 -> block-wide full-scan fallback
  }
  __syncthreads();
  if (tid == 0) {
    int acc = 0, no = 0;
    for (int r = 0; r < 32; ++r) {
      starts[r] = acc;
      acc += rowtot[r];
      if (rowtot[r] == 0) ovf_list[no++] = r;
    }
    starts[32] = acc; nP = acc; nOvf = no;
  }
  __syncthreads();
  {
    const int r = tid >> 4, g = tid & 15;   // 512 threads cover [32][16]
    if (rowtot[r]) {
      const int c = cnts8[r][g];
      const int base = starts[r] + grpoff[r][g];
      const int sb = g * GCAP;
      for (int j = 0; j < c; ++j) pidx[base + j] = s_slots[r][sb + j];
    }
  }
  if (tid < 32) {
    const int r = tid;
    if (rowtot[r]) {
      const int c = cnts8[r][16];
      const int base = starts[r] + grpoff[r][16];
      for (int j = 0; j < c; ++j) pidx[base + j] = s_slots[r][GSLOTS + j];
    }
  }
  __syncthreads();

  const int P = nP;
  for (int p = tid; p < P; p += 512) {
    // row lookup: largest r with starts[r] <= p (5-step binary search)
    int lo = 0, hi = 32;
#pragma unroll
    for (int s = 0; s < 5; ++s) {
      int mid = (lo + hi) >> 1;
      if (starts[mid] <= p) lo = mid; else hi = mid;
    }
    const int r = lo, idx = (int)pidx[p];
    float D = np_dist(zrows[r], emb + (size_t)idx * 256, A_s[r]);
    u64 key = ((u64)__float_as_uint(D) << 16) | (u32)idx;
    atomicMin(&best_s[r], key);
  }
  __syncthreads();

  // overflow fallback (spill>OCAP, ~never): block-wide scan
  for (int i = 0; i < nOvf; ++i) {
    const int r = ovf_list[i];
    for (int idx = tid; idx < NCODE; idx += 512) {
      float D = np_dist(zrows[r], emb + (size_t)idx * 256, A_s[r]);
      u64 k = ((u64)__float_as_uint(D) << 16) | (u32)idx;
      atomicMin(&best_s[r], k);
    }
  }
  if (nOvf) __syncthreads();

  if (tid < 32) {
    const int r = tid;
    const u64 k = best_s[r];
    const int bidx = (int)(k & 0xFFFF);
    widx_s[r] = bidx;
    out_idx[n0 + r] = (float)bidx;
    D_s[r] = __uint_as_float((u32)(k >> 16));
  }
  __syncthreads();
  if (tid == 0) {
    float s = 0.f;
    for (int r = 0; r < 32; ++r) s += D_s[r];
    atomicAdd(loss_ws, s);
    __threadfence();
    int t = atomicAdd(ctr, 1);
    if (t == 511)
      *out_loss = atomicAdd(loss_ws, 0.0f) * (1.25f / 4194304.0f);
  }

  {
    const int col = tid & 255, hi = tid >> 8;
#pragma unroll
    for (int wi0 = 0; wi0 < 16; ++wi0) {
      const int wi = wi0 * 2 + hi;
      zrows[wi][col] = emb[(size_t)widx_s[wi] * 256 + col];
    }
  }
  __syncthreads();
  {
    const int w = tid & 31, c0 = (tid >> 5) & 7, hi = tid >> 8;
    float* dst = z_st + (size_t)b * 262144 + h * 32 + w;
#pragma unroll
    for (int cj = 0; cj < 16; ++cj) {
      int c = c0 + (cj * 2 + hi) * 8;
      dst[(size_t)c * 1024] = zrows[w][c];
    }
  }
}

extern "C" void kernel_launch(void* const* d_in, const int* in_sizes, int n_in,
                              void* d_out, int out_size, void* d_ws, size_t ws_size,
                              hipStream_t stream) {
  const float* z = (const float*)d_in[0];     // fp32 [16,256,32,32]
  const float* emb = (const float*)d_in[1];   // fp32 [8192,256]
  char* ws = (char*)d_ws;
  char* eb8 = ws + OFF_EB8;
  float* loss_ws = (float*)(ws + OFF_LOSS);
  int* ctr = (int*)(ws + OFF_CTR);
  float* out = (float*)d_out;
  float* out_loss = out + ZN;       // output 1
  float* out_idx = out + ZN + 1;    // output 2

  eprep_kernel<<<128, 256, 0, stream>>>(emb, eb8, loss_ws, ctr);
  fused_kernel<<<512, 512, 0, stream>>>(z, eb8, emb, loss_ws, ctr,
                                        out, out_loss, out_idx);
}